// Round 20
// baseline (91.980 us; speedup 1.0000x reference)
//
#include <hip/hip_runtime.h>
#include <hip/hip_bf16.h>

using u16 = unsigned short;
using u32 = unsigned int;
using u64 = unsigned long long;
typedef __attribute__((ext_vector_type(8))) short short8;
typedef __attribute__((ext_vector_type(4))) float f32x4;
typedef __attribute__((ext_vector_type(16))) float f32x16;
typedef __attribute__((ext_vector_type(4))) u32 u32x4;

constexpr int kB = 16, kNL = 512, kEL = 1024, kD = 256, kH = 8, kHD = 32;
constexpr int kS = kNL + kEL;      // 1536
constexpr int kM1 = kB * kNL;      // 8192
constexpr float kScale = 0.17677669529663687f;  // 1/sqrt(32)
constexpr float kLog2e = 1.4426950408889634f;
constexpr float kQS = kScale * kLog2e;          // folded into q at GEMM1 epilogue
constexpr float kEps = 1e-5f;

__device__ __forceinline__ u16 f2bh(float f) {
    __hip_bfloat16 h = __float2bfloat16(f);   // RNE
    return __builtin_bit_cast(u16, h);
}
__device__ __forceinline__ u32 packbf(float lo, float hi) {  // trunc pair (P >= 0)
    return (__float_as_uint(hi) & 0xffff0000u) | (__float_as_uint(lo) >> 16);
}
__device__ __forceinline__ void load4(const float* p, float* o) {
    float4 v = *reinterpret_cast<const float4*>(p);
    o[0] = v.x; o[1] = v.y; o[2] = v.z; o[3] = v.w;
}
__device__ __forceinline__ f32x16 fzero16() {
    f32x16 z;
    #pragma unroll
    for (int i = 0; i < 16; ++i) z[i] = 0.f;
    return z;
}

// ---------- prep: flat 1D grid of exactly 8640 blocks, range-dispatched ----------
__global__ __launch_bounds__(256) void prep_k(
    const float* __restrict__ W1, const float* __restrict__ W2,
    const float* __restrict__ l1w, const float* __restrict__ l2w,
    const float* __restrict__ nodef, const float* __restrict__ edgef,
    const u32* __restrict__ mask,
    u16* __restrict__ Wt1, u16* __restrict__ Wt2,
    u16* __restrict__ Wt3, u16* __restrict__ Wt4,
    u16* __restrict__ nodeb, u16* __restrict__ edgeb,
    u32* __restrict__ Mw)
{
    const int vb = blockIdx.x, t = threadIdx.x;
    if (vb < 320) {   // weight transpose
        const int sec = (vb < 192) ? 0 : 1;
        const int bid = (sec == 0) ? vb : vb - 192;
        const int N = (sec == 0) ? 768 : 512;
        const float* src = (sec == 0) ? W1 : W2;
        u16* dst = (sec == 0) ? Wt1 : Wt2;
        const int tk = bid / (N / 32), tn = bid % (N / 32);
        __shared__ float T[32][33];
        {
            const int k = t >> 3, n4 = (t & 7) * 4;
            float v[4]; load4(src + (size_t)(tk * 32 + k) * N + tn * 32 + n4, v);
            T[n4+0][k] = v[0]; T[n4+1][k] = v[1]; T[n4+2][k] = v[2]; T[n4+3][k] = v[3];
        }
        __syncthreads();
        {
            const int n = t >> 3, k4 = (t & 7) * 4;
            ushort4 o = {f2bh(T[n][k4+0]), f2bh(T[n][k4+1]),
                         f2bh(T[n][k4+2]), f2bh(T[n][k4+3])};
            *reinterpret_cast<ushort4*>(dst + (size_t)(tn*32 + n) * 256 + tk*32 + k4) = o;
        }
        return;
    }
    if (vb < 448) {   // l1w/l2w casts
        const int sec = (vb < 384) ? 0 : 1;
        const int bid = (sec == 0) ? vb - 320 : vb - 384;
        const float* src = (sec == 0) ? l1w : l2w;
        u16* dst = (sec == 0) ? Wt3 : Wt4;
        const int i = bid * 1024 + t * 4;
        float v[4]; load4(src + i, v);
        ushort4 o = {f2bh(v[0]), f2bh(v[1]), f2bh(v[2]), f2bh(v[3])};
        *reinterpret_cast<ushort4*>(dst + i) = o;
        return;
    }
    if (vb < 6592) {  // node / edge bf16 casts
        const int sec = (vb < 2496) ? 0 : 1;
        const int bid = (sec == 0) ? vb - 448 : vb - 2496;
        const float* src = (sec == 0) ? nodef : edgef;
        u16* dst = (sec == 0) ? nodeb : edgeb;
        const int i = bid * 1024 + t * 4;
        float v[4]; load4(src + i, v);
        ushort4 o = {f2bh(v[0]), f2bh(v[1]), f2bh(v[2]), f2bh(v[3])};
        *reinterpret_cast<ushort4*>(dst + i) = o;
        return;
    }
    {   // mask bitmap
        const int bid = vb - 6592;
        const int row = bid * 4 + (t >> 6);
        const int l = t & 63;
        const u32* mr = mask + (size_t)row * (kS / 4);
        u32 word = 0;
        #pragma unroll
        for (int k = 0; k < 6; ++k) {
            const u32 v = mr[k * 64 + l];
            const u64 bal = __ballot(v != 0);
            word |= (((bal) & 0xffffull) ? 1u : 0u) << (k * 4 + 0);
            word |= (((bal >> 16) & 0xffffull) ? 1u : 0u) << (k * 4 + 1);
            word |= (((bal >> 32) & 0xffffull) ? 1u : 0u) << (k * 4 + 2);
            word |= (((bal >> 48) & 0xffffull) ? 1u : 0u) << (k * 4 + 3);
        }
        if (l == 0) Mw[row] = word;
    }
}

// ---------- GEMM body (128x128 tile, 4 waves 2x2, BK=32) ----------
template<int N, int K, int MODE>
__device__ __forceinline__ void gemm_body128(
    const u16* __restrict__ A, const u16* __restrict__ Wt,
    const float* __restrict__ bias,
    void* __restrict__ o0v, void* __restrict__ o1v, void* __restrict__ o2v,
    int bx, int by, u16* AsB, u16* BsB)
{
    const int t = threadIdx.x;
    const int w = t >> 6, l = t & 63;
    const int wr = w >> 1, wc = w & 1;
    const int lq = l & 15, lg = l >> 4;
    const int bm = bx * 128, bn = by * 128;

    f32x4 acc[4][4];
    #pragma unroll
    for (int mi = 0; mi < 4; ++mi)
        #pragma unroll
        for (int ni = 0; ni < 4; ++ni) acc[mi][ni] = (f32x4){0.f, 0.f, 0.f, 0.f};

    auto stage = [&](int buf, int kk) {
        u16* As = AsB + buf * (128 * 40);
        u16* Bs = BsB + buf * (128 * 40);
        const int m = t >> 1, kh = (t & 1) * 16;
        const u16* ap = A + (size_t)(bm + m) * K + kk + kh;
        *reinterpret_cast<short8*>(&As[m * 40 + kh]) = *reinterpret_cast<const short8*>(ap);
        *reinterpret_cast<short8*>(&As[m * 40 + kh + 8]) = *reinterpret_cast<const short8*>(ap + 8);
        const u16* bp = Wt + (size_t)(bn + m) * K + kk + kh;
        *reinterpret_cast<short8*>(&Bs[m * 40 + kh]) = *reinterpret_cast<const short8*>(bp);
        *reinterpret_cast<short8*>(&Bs[m * 40 + kh + 8]) = *reinterpret_cast<const short8*>(bp + 8);
    };

    stage(0, 0);
    __syncthreads();
    int buf = 0;
    for (int kk = 0; kk < K; kk += 32) {
        if (kk + 32 < K) stage(buf ^ 1, kk + 32);
        const u16* As = AsB + buf * (128 * 40);
        const u16* Bs = BsB + buf * (128 * 40);
        short8 bf[4];
        #pragma unroll
        for (int ni = 0; ni < 4; ++ni)
            bf[ni] = *reinterpret_cast<const short8*>(
                &Bs[(wc * 64 + ni * 16 + lq) * 40 + lg * 8]);
        #pragma unroll
        for (int mi = 0; mi < 4; ++mi) {
            const short8 af = *reinterpret_cast<const short8*>(
                &As[(wr * 64 + mi * 16 + lq) * 40 + lg * 8]);
            #pragma unroll
            for (int ni = 0; ni < 4; ++ni)
                acc[mi][ni] = __builtin_amdgcn_mfma_f32_16x16x32_bf16(
                    af, bf[ni], acc[mi][ni], 0, 0, 0);
        }
        __syncthreads();
        buf ^= 1;
    }

    #pragma unroll
    for (int mi = 0; mi < 4; ++mi) {
        #pragma unroll
        for (int ni = 0; ni < 4; ++ni) {
            const int cg = bn + wc * 64 + ni * 16 + lq;
            const int rg0 = bm + wr * 64 + mi * 16 + lg * 4;
            const float bv = bias[cg];
            float y[4];
            #pragma unroll
            for (int r = 0; r < 4; ++r) y[r] = acc[mi][ni][r] + bv;
            if constexpr (MODE == 0) {
                u16* qo = (u16*)o0v; u16* ko = (u16*)o1v; u16* vt = (u16*)o2v;
                const int bidx = rg0 >> 9, key = rg0 & 511;
                if (cg < 256) {
                    #pragma unroll
                    for (int r = 0; r < 4; ++r)
                        qo[(size_t)(rg0 + r) * kD + cg] = f2bh(y[r] * kQS);
                } else if (cg < 512) {
                    #pragma unroll
                    for (int r = 0; r < 4; ++r)
                        ko[((size_t)bidx * kS + key + r) * kD + (cg - 256)] = f2bh(y[r]);
                } else {
                    const int d0 = cg - 512, hh = d0 >> 5, dd = d0 & 31;
                    ushort4 o = {f2bh(y[0]), f2bh(y[1]), f2bh(y[2]), f2bh(y[3])};
                    *reinterpret_cast<ushort4*>(
                        vt + ((size_t)(bidx * kH + hh) * kHD + dd) * kS + key) = o;
                }
            } else {
                u16* ko = (u16*)o0v; u16* vt = (u16*)o1v;
                const int bidx = rg0 >> 10, key = kNL + (rg0 & 1023);
                if (cg < 256) {
                    #pragma unroll
                    for (int r = 0; r < 4; ++r)
                        ko[((size_t)bidx * kS + key + r) * kD + cg] = f2bh(y[r]);
                } else {
                    const int d0 = cg - 256, hh = d0 >> 5, dd = d0 & 31;
                    ushort4 o = {f2bh(y[0]), f2bh(y[1]), f2bh(y[2]), f2bh(y[3])};
                    *reinterpret_cast<ushort4*>(
                        vt + ((size_t)(bidx * kH + hh) * kHD + dd) * kS + key) = o;
                }
            }
        }
    }
}

// one launch for both projection GEMMs (896 blocks: 384 node + 512 edge)
__global__ __launch_bounds__(256) void qkv_both(
    const u16* __restrict__ nxb, const u16* __restrict__ exb,
    const u16* __restrict__ wt1, const u16* __restrict__ wt2,
    const float* __restrict__ b1, const float* __restrict__ b2,
    u16* __restrict__ qb, u16* __restrict__ kb, u16* __restrict__ vt)
{
    __shared__ u16 AsB[2 * 128 * 40];
    __shared__ u16 BsB[2 * 128 * 40];
    const int bid = blockIdx.x;
    if (bid < 384) {
        gemm_body128<768, 256, 0>(nxb, wt1, b1, qb, kb, vt,
                                  bid & 63, bid >> 6, AsB, BsB);
    } else {
        const int r = bid - 384;
        gemm_body128<512, 256, 1>(exb, wt2, b2, kb, vt, nullptr,
                                  r & 127, r >> 7, AsB, BsB);
    }
}

// ---------- FFN1: relu(A@W^T+b) -> bf16, BM=64 BN=128 ----------
__global__ __launch_bounds__(256) void ffn1_k(
    const u16* __restrict__ A, const u16* __restrict__ Wt,
    const float* __restrict__ bias, u16* __restrict__ out)
{
    __shared__ u16 AsB[2][64 * 40];
    __shared__ u16 BsB[2][128 * 40];
    const int t = threadIdx.x;
    const int w = t >> 6, l = t & 63;
    const int wr = w >> 1, wc = w & 1;
    const int lq = l & 15, lg = l >> 4;
    const int bm = blockIdx.x * 64, bn = blockIdx.y * 128;
    constexpr int K = 256;

    f32x4 acc[2][4];
    #pragma unroll
    for (int mi = 0; mi < 2; ++mi)
        #pragma unroll
        for (int ni = 0; ni < 4; ++ni) acc[mi][ni] = (f32x4){0.f, 0.f, 0.f, 0.f};

    auto stage = [&](int buf, int kk) {
        {
            const int m = t >> 2, kq = (t & 3) * 8;
            *reinterpret_cast<short8*>(&AsB[buf][m * 40 + kq]) =
                *reinterpret_cast<const short8*>(A + (size_t)(bm + m) * K + kk + kq);
        }
        {
            const int n = t >> 1, kh = (t & 1) * 16;
            const u16* bp = Wt + (size_t)(bn + n) * K + kk + kh;
            *reinterpret_cast<short8*>(&BsB[buf][n * 40 + kh]) =
                *reinterpret_cast<const short8*>(bp);
            *reinterpret_cast<short8*>(&BsB[buf][n * 40 + kh + 8]) =
                *reinterpret_cast<const short8*>(bp + 8);
        }
    };

    stage(0, 0);
    __syncthreads();
    int buf = 0;
    for (int kk = 0; kk < K; kk += 32) {
        if (kk + 32 < K) stage(buf ^ 1, kk + 32);
        short8 bf[4];
        #pragma unroll
        for (int ni = 0; ni < 4; ++ni)
            bf[ni] = *reinterpret_cast<const short8*>(
                &BsB[buf][(wc * 64 + ni * 16 + lq) * 40 + lg * 8]);
        #pragma unroll
        for (int mi = 0; mi < 2; ++mi) {
            const short8 af = *reinterpret_cast<const short8*>(
                &AsB[buf][(wr * 32 + mi * 16 + lq) * 40 + lg * 8]);
            #pragma unroll
            for (int ni = 0; ni < 4; ++ni)
                acc[mi][ni] = __builtin_amdgcn_mfma_f32_16x16x32_bf16(
                    af, bf[ni], acc[mi][ni], 0, 0, 0);
        }
        __syncthreads();
        buf ^= 1;
    }

    #pragma unroll
    for (int mi = 0; mi < 2; ++mi) {
        #pragma unroll
        for (int ni = 0; ni < 4; ++ni) {
            const int cg = bn + wc * 64 + ni * 16 + lq;
            const int rg0 = bm + wr * 32 + mi * 16 + lg * 4;
            const float bv = bias[cg];
            #pragma unroll
            for (int r = 0; r < 4; ++r)
                out[(size_t)(rg0 + r) * 256 + cg] = f2bh(fmaxf(acc[mi][ni][r] + bv, 0.f));
        }
    }
}

// ---------- FFN2 + residual + LN2 fused: BM=32, BN=256 (full row) ----------
__global__ __launch_bounds__(256) void ffn2_ln2_k(
    const u16* __restrict__ A, const u16* __restrict__ Wt,
    const float* __restrict__ bias, const float* __restrict__ xb,
    const float* __restrict__ gam, const float* __restrict__ bet,
    float* __restrict__ out)
{
    __shared__ __align__(16) char smem[46080];
    u16* AsB = (u16*)smem;                       // 2 x 32*40
    u16* BsB = (u16*)(smem + 2 * 32 * 40 * 2);   // 2 x 256*40
    float* lnb = (float*)smem;                   // 32 x 260 (reused after K-loop)
    const int t = threadIdx.x;
    const int w = t >> 6, l = t & 63;
    const int wr = w >> 1, wc = w & 1;
    const int lq = l & 15, lg = l >> 4;
    const int bm = blockIdx.x * 32;
    constexpr int K = 256;

    f32x4 acc[8];
    #pragma unroll
    for (int ni = 0; ni < 8; ++ni) acc[ni] = (f32x4){0.f, 0.f, 0.f, 0.f};

    auto stage = [&](int buf, int kk) {
        {
            const int m = t >> 3, kq = (t & 7) * 4;
            *reinterpret_cast<ushort4*>(&AsB[buf * 32 * 40 + m * 40 + kq]) =
                *reinterpret_cast<const ushort4*>(A + (size_t)(bm + m) * K + kk + kq);
        }
        {
            const int n = t;
            const u16* bp = Wt + (size_t)n * K + kk;
            u16* dst = &BsB[buf * 256 * 40 + n * 40];
            #pragma unroll
            for (int j = 0; j < 4; ++j)
                *reinterpret_cast<short8*>(dst + j * 8) =
                    *reinterpret_cast<const short8*>(bp + j * 8);
        }
    };

    stage(0, 0);
    __syncthreads();
    int buf = 0;
    for (int kk = 0; kk < K; kk += 32) {
        if (kk + 32 < K) stage(buf ^ 1, kk + 32);
        short8 bf[8];
        #pragma unroll
        for (int ni = 0; ni < 8; ++ni)
            bf[ni] = *reinterpret_cast<const short8*>(
                &BsB[buf * 256 * 40 + (wc * 128 + ni * 16 + lq) * 40 + lg * 8]);
        const short8 af = *reinterpret_cast<const short8*>(
            &AsB[buf * 32 * 40 + (wr * 16 + lq) * 40 + lg * 8]);
        #pragma unroll
        for (int ni = 0; ni < 8; ++ni)
            acc[ni] = __builtin_amdgcn_mfma_f32_16x16x32_bf16(af, bf[ni], acc[ni], 0, 0, 0);
        __syncthreads();
        buf ^= 1;
    }

    #pragma unroll
    for (int ni = 0; ni < 8; ++ni) {
        const int cg = wc * 128 + ni * 16 + lq;
        const int rl0 = wr * 16 + lg * 4;
        const float bv = bias[cg];
        #pragma unroll
        for (int r = 0; r < 4; ++r)
            lnb[(rl0 + r) * 260 + cg] = acc[ni][r] + bv;
    }
    __syncthreads();

    #pragma unroll
    for (int rr = 0; rr < 8; ++rr) {
        const int rl = w * 8 + rr;
        const int row = bm + rl;
        float xv[4];
        float4 yv = *reinterpret_cast<const float4*>(&lnb[rl * 260 + l * 4]);
        float rv[4];
        load4(xb + (size_t)row * kD + l * 4, rv);
        xv[0] = yv.x + rv[0]; xv[1] = yv.y + rv[1];
        xv[2] = yv.z + rv[2]; xv[3] = yv.w + rv[3];
        float s = xv[0] + xv[1] + xv[2] + xv[3];
        float q = xv[0]*xv[0] + xv[1]*xv[1] + xv[2]*xv[2] + xv[3]*xv[3];
        #pragma unroll
        for (int off = 1; off < 64; off <<= 1) {
            s += __shfl_xor(s, off);
            q += __shfl_xor(q, off);
        }
        const float mean = s * (1.0f / kD);
        const float var = q * (1.0f / kD) - mean * mean;
        const float rs = rsqrtf(var + kEps);
        float gv[4], bv[4];
        load4(gam + l * 4, gv);
        load4(bet + l * 4, bv);
        float4 o;
        o.x = (xv[0] - mean) * rs * gv[0] + bv[0];
        o.y = (xv[1] - mean) * rs * gv[1] + bv[1];
        o.z = (xv[2] - mean) * rs * gv[2] + bv[2];
        o.w = (xv[3] - mean) * rs * gv[3] + bv[3];
        *reinterpret_cast<float4*>(out + (size_t)row * kD + l * 4) = o;
    }
}

// ---------- attention: 8 waves share LDS-staged K/V tiles; no split-K ----------
// Block = 512 thr = 8 waves x 32 q-rows (256 rows); 2 blocks per (b,h).
// Per tile: one coalesced 8KB stage (1 x b128/thread) feeds all 8 waves via
// ds_read. Global gather instrs per wave-tile: 8 -> 1 (the r14 lever, 8x).
__global__ __launch_bounds__(512) void attn_mfma(
    const u16* __restrict__ Qb, const u16* __restrict__ Kb,
    const u16* __restrict__ VTb, const unsigned char* __restrict__ mask,
    const u32* __restrict__ Mw, float* __restrict__ O)
{
    __shared__ u16 Ks[2][64 * 40];   // K tile rows padded to 40 u16 (4-way max)
    __shared__ u16 Vs[2][32 * 72];   // V^T tile rows padded to 72 u16
    const int t = threadIdx.x;
    const int w = t >> 6, l = t & 63;
    const int q32 = l & 31, hi = l >> 5;
    const int bid = blockIdx.x;
    const int h = bid & 7;
    const int half = (bid >> 3) & 1;
    const int b = bid >> 4;
    const int qrow = half * 256 + w * 32 + q32;

    const u16* qp = Qb + ((size_t)(b * kNL) + qrow) * kD + h * kHD;
    const short8 qf0 = *reinterpret_cast<const short8*>(qp + hi * 8);
    const short8 qf1 = *reinterpret_cast<const short8*>(qp + 16 + hi * 8);

    const u16* kbase  = Kb  + ((size_t)b * kS) * kD + h * kHD;
    const u16* vtbase = VTb + ((size_t)(b * kH + h) * kHD) * kS;
    const unsigned char* mrow = mask + ((size_t)(b * kNL) + qrow) * kS;
    const u32 mbits = Mw[b * kNL + qrow];

    f32x16 acc = fzero16();
    float l_run = 0.f;

    auto stage = [&](int buf, int kt) {
        const int key0 = kt * 64;
        if (t < 256) {        // K tile: 64 rows x 32 dims
            const int r = t >> 2, c = t & 3;
            *reinterpret_cast<short8*>(&Ks[buf][r * 40 + c * 8]) =
                *reinterpret_cast<const short8*>(kbase + (size_t)(key0 + r) * kD + c * 8);
        } else {              // V^T tile: 32 dim-rows x 64 keys
            const int idx = t - 256;
            const int r = idx >> 3, c = idx & 7;
            *reinterpret_cast<short8*>(&Vs[buf][r * 72 + c * 8]) =
                *reinterpret_cast<const short8*>(vtbase + (size_t)r * kS + key0 + c * 8);
        }
    };

#define HALFG(kfA, kfB, vfA, vfB, keyh) do {                                   \
        f32x16 s = __builtin_amdgcn_mfma_f32_32x32x16_bf16(kfA, qf0, fzero16(), 0, 0, 0); \
        s = __builtin_amdgcn_mfma_f32_32x32x16_bf16(kfB, qf1, s, 0, 0, 0);     \
        float e[16];                                                           \
        _Pragma("unroll")                                                      \
        for (int n = 0; n < 16; ++n) e[n] = __builtin_amdgcn_exp2f(s[n]);      \
        if (cold) {                                                            \
            _Pragma("unroll")                                                  \
            for (int n = 0; n < 16; ++n) {                                     \
                const int key = (keyh) + (n & 3) + 8 * (n >> 2) + 4 * hi;      \
                if (mrow[key]) e[n] = 0.f;                                     \
            }                                                                  \
        }                                                                      \
        u32 pk[8];                                                             \
        _Pragma("unroll")                                                      \
        for (int qd = 0; qd < 4; ++qd) {                                       \
            l_run += (e[4*qd] + e[4*qd+1]) + (e[4*qd+2] + e[4*qd+3]);          \
            pk[2*qd]   = packbf(e[4*qd],   e[4*qd+1]);                         \
            pk[2*qd+1] = packbf(e[4*qd+2], e[4*qd+3]);                         \
        }                                                                      \
        {                                                                      \
            u32 xa = pk[0], ya = pk[2], xb_ = pk[1], yb_ = pk[3];              \
            asm("v_permlane32_swap_b32 %0, %1" : "+v"(xa), "+v"(ya));          \
            asm("v_permlane32_swap_b32 %0, %1" : "+v"(xb_), "+v"(yb_));        \
            const short8 pb = __builtin_bit_cast(short8, (u32x4){xa, xb_, ya, yb_}); \
            __builtin_amdgcn_s_setprio(1);                                     \
            acc = __builtin_amdgcn_mfma_f32_32x32x16_bf16(vfA, pb, acc, 0, 0, 0); \
            __builtin_amdgcn_s_setprio(0);                                     \
        }                                                                      \
        {                                                                      \
            u32 xa = pk[4], ya = pk[6], xb_ = pk[5], yb_ = pk[7];              \
            asm("v_permlane32_swap_b32 %0, %1" : "+v"(xa), "+v"(ya));          \
            asm("v_permlane32_swap_b32 %0, %1" : "+v"(xb_), "+v"(yb_));        \
            const short8 pb = __builtin_bit_cast(short8, (u32x4){xa, xb_, ya, yb_}); \
            __builtin_amdgcn_s_setprio(1);                                     \
            acc = __builtin_amdgcn_mfma_f32_32x32x16_bf16(vfB, pb, acc, 0, 0, 0); \
            __builtin_amdgcn_s_setprio(0);                                     \
        }                                                                      \
} while (0)

    stage(0, 0);
    __syncthreads();
    int buf = 0;
    for (int kt = 0; kt < 24; ++kt) {
        if (kt + 1 < 24) stage(buf ^ 1, kt + 1);   // issue-early: hides under compute
        const int key0 = kt * 64;
        const bool cold = __any(((mbits >> kt) & 1u) != 0u);
        // fragments from LDS (same per-lane layout as the old global gathers)
        const short8 a0 = *reinterpret_cast<const short8*>(&Ks[buf][q32 * 40 + hi * 8]);
        const short8 a1 = *reinterpret_cast<const short8*>(&Ks[buf][q32 * 40 + 16 + hi * 8]);
        const short8 a2 = *reinterpret_cast<const short8*>(&Ks[buf][(32 + q32) * 40 + hi * 8]);
        const short8 a3 = *reinterpret_cast<const short8*>(&Ks[buf][(32 + q32) * 40 + 16 + hi * 8]);
        const short8 v0 = *reinterpret_cast<const short8*>(&Vs[buf][q32 * 72 + hi * 8]);
        const short8 v1 = *reinterpret_cast<const short8*>(&Vs[buf][q32 * 72 + 16 + hi * 8]);
        const short8 v2 = *reinterpret_cast<const short8*>(&Vs[buf][q32 * 72 + 32 + hi * 8]);
        const short8 v3 = *reinterpret_cast<const short8*>(&Vs[buf][q32 * 72 + 48 + hi * 8]);
        HALFG(a0, a1, v0, v1, key0);
        HALFG(a2, a3, v2, v3, key0 + 32);
        __syncthreads();
        buf ^= 1;
    }
#undef HALFG

    l_run += __shfl_xor(l_run, 32);
    const float inv = (l_run > 0.f) ? 1.f / l_run : 0.f;
    float* orow = O + ((size_t)(b * kNL) + qrow) * kD + h * kHD;
    #pragma unroll
    for (int qd = 0; qd < 4; ++qd) {
        float4 o = {acc[4*qd+0] * inv, acc[4*qd+1] * inv,
                    acc[4*qd+2] * inv, acc[4*qd+3] * inv};
        *reinterpret_cast<float4*>(orow + qd * 8 + 4 * hi) = o;
    }
}

// out = LayerNorm(a + r) * gamma + beta, dual f32 + bf16 outputs.
__global__ __launch_bounds__(256) void ln_k(
    const float* __restrict__ a_, const float* __restrict__ r,
    const float* __restrict__ gam, const float* __restrict__ bet,
    float* __restrict__ out_, u16* __restrict__ outh)
{
    const int row = blockIdx.x * 4 + (threadIdx.x >> 6);
    const int lane = threadIdx.x & 63;
    const size_t base = (size_t)row * kD + lane * 4;
    float xv[4];
    load4(a_ + base, xv);
    float rv[4];
    load4(r + base, rv);
    #pragma unroll
    for (int t = 0; t < 4; ++t) xv[t] += rv[t];
    float s = xv[0] + xv[1] + xv[2] + xv[3];
    float q = xv[0]*xv[0] + xv[1]*xv[1] + xv[2]*xv[2] + xv[3]*xv[3];
    #pragma unroll
    for (int off = 1; off < 64; off <<= 1) {
        s += __shfl_xor(s, off);
        q += __shfl_xor(q, off);
    }
    const float mean = s * (1.0f / kD);
    const float var = q * (1.0f / kD) - mean * mean;
    const float rs = rsqrtf(var + kEps);
    float gv[4], bv[4];
    load4(gam + lane * 4, gv);
    load4(bet + lane * 4, bv);
    float y[4];
    #pragma unroll
    for (int t = 0; t < 4; ++t) y[t] = (xv[t] - mean) * rs * gv[t] + bv[t];
    float4 o = {y[0], y[1], y[2], y[3]};
    *reinterpret_cast<float4*>(out_ + base) = o;
    ushort4 ob = {f2bh(y[0]), f2bh(y[1]), f2bh(y[2]), f2bh(y[3])};
    *reinterpret_cast<ushort4*>(outh + base) = ob;
}

extern "C" void kernel_launch(void* const* d_in, const int* in_sizes, int n_in,
                              void* d_out, int out_size, void* d_ws, size_t ws_size,
                              hipStream_t stream)
{
    const float* node_x = (const float*)d_in[0];
    const float* edge_x = (const float*)d_in[1];
    const unsigned char* mask = (const unsigned char*)d_in[2];
    const float* W1  = (const float*)d_in[3];
    const float* b1  = (const float*)d_in[4];
    const float* W2  = (const float*)d_in[5];
    const float* b2  = (const float*)d_in[6];
    const float* l1w = (const float*)d_in[7];
    const float* l1b = (const float*)d_in[8];
    const float* l2w = (const float*)d_in[9];
    const float* l2b = (const float*)d_in[10];
    const float* g1  = (const float*)d_in[11];
    const float* be1 = (const float*)d_in[12];
    const float* g2  = (const float*)d_in[13];
    const float* be2 = (const float*)d_in[14];

    char* w = (char*)d_ws;
    u16*   qb  = (u16*)(w);                      // q bf16 4 MB   [0,4); later fh bf16
    u16*   wt1 = (u16*)(w + (4u<<20));           // 768x256 bf16
    u16*   wt2 = (u16*)(w + (4u<<20) + 393216);
    u16*   wt3 = (u16*)(w + (4u<<20) + 655360);
    u16*   wt4 = (u16*)(w + (4u<<20) + 786432);
    u32*   mw  = (u32*)(w + (4u<<20) + 917504);  // mask bitmap 32 KB
    u16*   nxb = (u16*)(w + (5u<<20));           // node bf16 4 MB  [5,9)
    u16*   exb = (u16*)(w + (9u<<20));           // edge bf16 8 MB  [9,17); later xbh
    u16*   kb  = (u16*)(w + (17u<<20));          // K bf16 12 MB    [17,30)
    u16*   vt  = (u16*)(w + (30u<<20));          // V^T bf16 12 MB  [30,43)
    float* cx  = (float*)(w + (43u<<20));        // ctx f32 8 MB    [43,52)
    float* xb  = (float*)(w + (52u<<20));        // x after LN1 f32 [52,61)
    u16*   xbh = exb;                            // LN1 bf16 out (edge_bf dead)
    u16*   fh  = qb;                             // ffn hidden bf16 (qb dead)

    prep_k<<<8640, 256, 0, stream>>>(
        W1, W2, l1w, l2w, node_x, edge_x, (const u32*)mask,
        wt1, wt2, wt3, wt4, nxb, exb, mw);
    qkv_both<<<896, 256, 0, stream>>>(nxb, exb, wt1, wt2, b1, b2, qb, kb, vt);
    attn_mfma<<<kB * 2 * 8, 512, 0, stream>>>(qb, kb, vt, mask, mw, cx);
    ln_k<<<kM1 / 4, 256, 0, stream>>>(node_x, cx, g1, be1, xb, xbh);
    ffn1_k<<<dim3(kM1 / 64, 2), 256, 0, stream>>>(xbh, wt3, l1b, fh);
    ffn2_ln2_k<<<kM1 / 32, 256, 0, stream>>>(fh, wt4, l2b, xb, g2, be2, (float*)d_out);
}

// Round 21
// 84.140 us; speedup vs baseline: 1.0932x; 1.0932x over previous
//
#include <hip/hip_runtime.h>
#include <hip/hip_bf16.h>

using u16 = unsigned short;
using u32 = unsigned int;
using u64 = unsigned long long;
typedef __attribute__((ext_vector_type(8))) short short8;
typedef __attribute__((ext_vector_type(4))) float f32x4;
typedef __attribute__((ext_vector_type(16))) float f32x16;
typedef __attribute__((ext_vector_type(4))) u32 u32x4;

constexpr int kB = 16, kNL = 512, kEL = 1024, kD = 256, kH = 8, kHD = 32;
constexpr int kS = kNL + kEL;      // 1536
constexpr int kM1 = kB * kNL;      // 8192
constexpr float kScale = 0.17677669529663687f;  // 1/sqrt(32)
constexpr float kLog2e = 1.4426950408889634f;
constexpr float kQS = kScale * kLog2e;          // folded into q at GEMM1 epilogue
constexpr float kEps = 1e-5f;

__device__ __forceinline__ u16 f2bh(float f) {
    __hip_bfloat16 h = __float2bfloat16(f);   // RNE
    return __builtin_bit_cast(u16, h);
}
__device__ __forceinline__ u32 packbf(float lo, float hi) {  // trunc pair (P >= 0)
    return (__float_as_uint(hi) & 0xffff0000u) | (__float_as_uint(lo) >> 16);
}
__device__ __forceinline__ void load4(const float* p, float* o) {
    float4 v = *reinterpret_cast<const float4*>(p);
    o[0] = v.x; o[1] = v.y; o[2] = v.z; o[3] = v.w;
}
__device__ __forceinline__ f32x16 fzero16() {
    f32x16 z;
    #pragma unroll
    for (int i = 0; i < 16; ++i) z[i] = 0.f;
    return z;
}

// ---------- prep: flat 1D grid of exactly 8640 blocks, range-dispatched ----------
__global__ __launch_bounds__(256) void prep_k(
    const float* __restrict__ W1, const float* __restrict__ W2,
    const float* __restrict__ l1w, const float* __restrict__ l2w,
    const float* __restrict__ nodef, const float* __restrict__ edgef,
    const u32* __restrict__ mask,
    u16* __restrict__ Wt1, u16* __restrict__ Wt2,
    u16* __restrict__ Wt3, u16* __restrict__ Wt4,
    u16* __restrict__ nodeb, u16* __restrict__ edgeb,
    u32* __restrict__ Mw)
{
    const int vb = blockIdx.x, t = threadIdx.x;
    if (vb < 320) {   // weight transpose
        const int sec = (vb < 192) ? 0 : 1;
        const int bid = (sec == 0) ? vb : vb - 192;
        const int N = (sec == 0) ? 768 : 512;
        const float* src = (sec == 0) ? W1 : W2;
        u16* dst = (sec == 0) ? Wt1 : Wt2;
        const int tk = bid / (N / 32), tn = bid % (N / 32);
        __shared__ float T[32][33];
        {
            const int k = t >> 3, n4 = (t & 7) * 4;
            float v[4]; load4(src + (size_t)(tk * 32 + k) * N + tn * 32 + n4, v);
            T[n4+0][k] = v[0]; T[n4+1][k] = v[1]; T[n4+2][k] = v[2]; T[n4+3][k] = v[3];
        }
        __syncthreads();
        {
            const int n = t >> 3, k4 = (t & 7) * 4;
            ushort4 o = {f2bh(T[n][k4+0]), f2bh(T[n][k4+1]),
                         f2bh(T[n][k4+2]), f2bh(T[n][k4+3])};
            *reinterpret_cast<ushort4*>(dst + (size_t)(tn*32 + n) * 256 + tk*32 + k4) = o;
        }
        return;
    }
    if (vb < 448) {   // l1w/l2w casts
        const int sec = (vb < 384) ? 0 : 1;
        const int bid = (sec == 0) ? vb - 320 : vb - 384;
        const float* src = (sec == 0) ? l1w : l2w;
        u16* dst = (sec == 0) ? Wt3 : Wt4;
        const int i = bid * 1024 + t * 4;
        float v[4]; load4(src + i, v);
        ushort4 o = {f2bh(v[0]), f2bh(v[1]), f2bh(v[2]), f2bh(v[3])};
        *reinterpret_cast<ushort4*>(dst + i) = o;
        return;
    }
    if (vb < 6592) {  // node / edge bf16 casts
        const int sec = (vb < 2496) ? 0 : 1;
        const int bid = (sec == 0) ? vb - 448 : vb - 2496;
        const float* src = (sec == 0) ? nodef : edgef;
        u16* dst = (sec == 0) ? nodeb : edgeb;
        const int i = bid * 1024 + t * 4;
        float v[4]; load4(src + i, v);
        ushort4 o = {f2bh(v[0]), f2bh(v[1]), f2bh(v[2]), f2bh(v[3])};
        *reinterpret_cast<ushort4*>(dst + i) = o;
        return;
    }
    {   // mask bitmap
        const int bid = vb - 6592;
        const int row = bid * 4 + (t >> 6);
        const int l = t & 63;
        const u32* mr = mask + (size_t)row * (kS / 4);
        u32 word = 0;
        #pragma unroll
        for (int k = 0; k < 6; ++k) {
            const u32 v = mr[k * 64 + l];
            const u64 bal = __ballot(v != 0);
            word |= (((bal) & 0xffffull) ? 1u : 0u) << (k * 4 + 0);
            word |= (((bal >> 16) & 0xffffull) ? 1u : 0u) << (k * 4 + 1);
            word |= (((bal >> 32) & 0xffffull) ? 1u : 0u) << (k * 4 + 2);
            word |= (((bal >> 48) & 0xffffull) ? 1u : 0u) << (k * 4 + 3);
        }
        if (l == 0) Mw[row] = word;
    }
}

// ---------- GEMM body (128x128 tile, 4 waves 2x2, BK=32) ----------
template<int N, int K, int MODE>
__device__ __forceinline__ void gemm_body128(
    const u16* __restrict__ A, const u16* __restrict__ Wt,
    const float* __restrict__ bias,
    void* __restrict__ o0v, void* __restrict__ o1v, void* __restrict__ o2v,
    int bx, int by, u16* AsB, u16* BsB)
{
    const int t = threadIdx.x;
    const int w = t >> 6, l = t & 63;
    const int wr = w >> 1, wc = w & 1;
    const int lq = l & 15, lg = l >> 4;
    const int bm = bx * 128, bn = by * 128;

    f32x4 acc[4][4];
    #pragma unroll
    for (int mi = 0; mi < 4; ++mi)
        #pragma unroll
        for (int ni = 0; ni < 4; ++ni) acc[mi][ni] = (f32x4){0.f, 0.f, 0.f, 0.f};

    auto stage = [&](int buf, int kk) {
        u16* As = AsB + buf * (128 * 40);
        u16* Bs = BsB + buf * (128 * 40);
        const int m = t >> 1, kh = (t & 1) * 16;
        const u16* ap = A + (size_t)(bm + m) * K + kk + kh;
        *reinterpret_cast<short8*>(&As[m * 40 + kh]) = *reinterpret_cast<const short8*>(ap);
        *reinterpret_cast<short8*>(&As[m * 40 + kh + 8]) = *reinterpret_cast<const short8*>(ap + 8);
        const u16* bp = Wt + (size_t)(bn + m) * K + kk + kh;
        *reinterpret_cast<short8*>(&Bs[m * 40 + kh]) = *reinterpret_cast<const short8*>(bp);
        *reinterpret_cast<short8*>(&Bs[m * 40 + kh + 8]) = *reinterpret_cast<const short8*>(bp + 8);
    };

    stage(0, 0);
    __syncthreads();
    int buf = 0;
    for (int kk = 0; kk < K; kk += 32) {
        if (kk + 32 < K) stage(buf ^ 1, kk + 32);
        const u16* As = AsB + buf * (128 * 40);
        const u16* Bs = BsB + buf * (128 * 40);
        short8 bf[4];
        #pragma unroll
        for (int ni = 0; ni < 4; ++ni)
            bf[ni] = *reinterpret_cast<const short8*>(
                &Bs[(wc * 64 + ni * 16 + lq) * 40 + lg * 8]);
        #pragma unroll
        for (int mi = 0; mi < 4; ++mi) {
            const short8 af = *reinterpret_cast<const short8*>(
                &As[(wr * 64 + mi * 16 + lq) * 40 + lg * 8]);
            #pragma unroll
            for (int ni = 0; ni < 4; ++ni)
                acc[mi][ni] = __builtin_amdgcn_mfma_f32_16x16x32_bf16(
                    af, bf[ni], acc[mi][ni], 0, 0, 0);
        }
        __syncthreads();
        buf ^= 1;
    }

    #pragma unroll
    for (int mi = 0; mi < 4; ++mi) {
        #pragma unroll
        for (int ni = 0; ni < 4; ++ni) {
            const int cg = bn + wc * 64 + ni * 16 + lq;
            const int rg0 = bm + wr * 64 + mi * 16 + lg * 4;
            const float bv = bias[cg];
            float y[4];
            #pragma unroll
            for (int r = 0; r < 4; ++r) y[r] = acc[mi][ni][r] + bv;
            if constexpr (MODE == 0) {
                u16* qo = (u16*)o0v; u16* ko = (u16*)o1v; u16* vt = (u16*)o2v;
                const int bidx = rg0 >> 9, key = rg0 & 511;
                if (cg < 256) {
                    #pragma unroll
                    for (int r = 0; r < 4; ++r)
                        qo[(size_t)(rg0 + r) * kD + cg] = f2bh(y[r] * kQS);
                } else if (cg < 512) {
                    #pragma unroll
                    for (int r = 0; r < 4; ++r)
                        ko[((size_t)bidx * kS + key + r) * kD + (cg - 256)] = f2bh(y[r]);
                } else {
                    const int d0 = cg - 512, hh = d0 >> 5, dd = d0 & 31;
                    ushort4 o = {f2bh(y[0]), f2bh(y[1]), f2bh(y[2]), f2bh(y[3])};
                    *reinterpret_cast<ushort4*>(
                        vt + ((size_t)(bidx * kH + hh) * kHD + dd) * kS + key) = o;
                }
            } else {
                u16* ko = (u16*)o0v; u16* vt = (u16*)o1v;
                const int bidx = rg0 >> 10, key = kNL + (rg0 & 1023);
                if (cg < 256) {
                    #pragma unroll
                    for (int r = 0; r < 4; ++r)
                        ko[((size_t)bidx * kS + key + r) * kD + cg] = f2bh(y[r]);
                } else {
                    const int d0 = cg - 256, hh = d0 >> 5, dd = d0 & 31;
                    ushort4 o = {f2bh(y[0]), f2bh(y[1]), f2bh(y[2]), f2bh(y[3])};
                    *reinterpret_cast<ushort4*>(
                        vt + ((size_t)(bidx * kH + hh) * kHD + dd) * kS + key) = o;
                }
            }
        }
    }
}

// one launch for both projection GEMMs (896 blocks: 384 node + 512 edge)
__global__ __launch_bounds__(256) void qkv_both(
    const u16* __restrict__ nxb, const u16* __restrict__ exb,
    const u16* __restrict__ wt1, const u16* __restrict__ wt2,
    const float* __restrict__ b1, const float* __restrict__ b2,
    u16* __restrict__ qb, u16* __restrict__ kb, u16* __restrict__ vt)
{
    __shared__ u16 AsB[2 * 128 * 40];
    __shared__ u16 BsB[2 * 128 * 40];
    const int bid = blockIdx.x;
    if (bid < 384) {
        gemm_body128<768, 256, 0>(nxb, wt1, b1, qb, kb, vt,
                                  bid & 63, bid >> 6, AsB, BsB);
    } else {
        const int r = bid - 384;
        gemm_body128<512, 256, 1>(exb, wt2, b2, kb, vt, nullptr,
                                  r & 127, r >> 7, AsB, BsB);
    }
}

// ---------- FFN1: relu(A@W^T+b) -> bf16, BM=64 BN=128 ----------
__global__ __launch_bounds__(256) void ffn1_k(
    const u16* __restrict__ A, const u16* __restrict__ Wt,
    const float* __restrict__ bias, u16* __restrict__ out)
{
    __shared__ u16 AsB[2][64 * 40];
    __shared__ u16 BsB[2][128 * 40];
    const int t = threadIdx.x;
    const int w = t >> 6, l = t & 63;
    const int wr = w >> 1, wc = w & 1;
    const int lq = l & 15, lg = l >> 4;
    const int bm = blockIdx.x * 64, bn = blockIdx.y * 128;
    constexpr int K = 256;

    f32x4 acc[2][4];
    #pragma unroll
    for (int mi = 0; mi < 2; ++mi)
        #pragma unroll
        for (int ni = 0; ni < 4; ++ni) acc[mi][ni] = (f32x4){0.f, 0.f, 0.f, 0.f};

    auto stage = [&](int buf, int kk) {
        {
            const int m = t >> 2, kq = (t & 3) * 8;
            *reinterpret_cast<short8*>(&AsB[buf][m * 40 + kq]) =
                *reinterpret_cast<const short8*>(A + (size_t)(bm + m) * K + kk + kq);
        }
        {
            const int n = t >> 1, kh = (t & 1) * 16;
            const u16* bp = Wt + (size_t)(bn + n) * K + kk + kh;
            *reinterpret_cast<short8*>(&BsB[buf][n * 40 + kh]) =
                *reinterpret_cast<const short8*>(bp);
            *reinterpret_cast<short8*>(&BsB[buf][n * 40 + kh + 8]) =
                *reinterpret_cast<const short8*>(bp + 8);
        }
    };

    stage(0, 0);
    __syncthreads();
    int buf = 0;
    for (int kk = 0; kk < K; kk += 32) {
        if (kk + 32 < K) stage(buf ^ 1, kk + 32);
        short8 bf[4];
        #pragma unroll
        for (int ni = 0; ni < 4; ++ni)
            bf[ni] = *reinterpret_cast<const short8*>(
                &BsB[buf][(wc * 64 + ni * 16 + lq) * 40 + lg * 8]);
        #pragma unroll
        for (int mi = 0; mi < 2; ++mi) {
            const short8 af = *reinterpret_cast<const short8*>(
                &AsB[buf][(wr * 32 + mi * 16 + lq) * 40 + lg * 8]);
            #pragma unroll
            for (int ni = 0; ni < 4; ++ni)
                acc[mi][ni] = __builtin_amdgcn_mfma_f32_16x16x32_bf16(
                    af, bf[ni], acc[mi][ni], 0, 0, 0);
        }
        __syncthreads();
        buf ^= 1;
    }

    #pragma unroll
    for (int mi = 0; mi < 2; ++mi) {
        #pragma unroll
        for (int ni = 0; ni < 4; ++ni) {
            const int cg = bn + wc * 64 + ni * 16 + lq;
            const int rg0 = bm + wr * 32 + mi * 16 + lg * 4;
            const float bv = bias[cg];
            #pragma unroll
            for (int r = 0; r < 4; ++r)
                out[(size_t)(rg0 + r) * 256 + cg] = f2bh(fmaxf(acc[mi][ni][r] + bv, 0.f));
        }
    }
}

// ---------- FFN2 + residual + LN2 fused: BM=32, BN=256 (full row) ----------
__global__ __launch_bounds__(256) void ffn2_ln2_k(
    const u16* __restrict__ A, const u16* __restrict__ Wt,
    const float* __restrict__ bias, const float* __restrict__ xb,
    const float* __restrict__ gam, const float* __restrict__ bet,
    float* __restrict__ out)
{
    __shared__ __align__(16) char smem[46080];
    u16* AsB = (u16*)smem;                       // 2 x 32*40
    u16* BsB = (u16*)(smem + 2 * 32 * 40 * 2);   // 2 x 256*40
    float* lnb = (float*)smem;                   // 32 x 260 (reused after K-loop)
    const int t = threadIdx.x;
    const int w = t >> 6, l = t & 63;
    const int wr = w >> 1, wc = w & 1;
    const int lq = l & 15, lg = l >> 4;
    const int bm = blockIdx.x * 32;
    constexpr int K = 256;

    f32x4 acc[8];
    #pragma unroll
    for (int ni = 0; ni < 8; ++ni) acc[ni] = (f32x4){0.f, 0.f, 0.f, 0.f};

    auto stage = [&](int buf, int kk) {
        {
            const int m = t >> 3, kq = (t & 7) * 4;
            *reinterpret_cast<ushort4*>(&AsB[buf * 32 * 40 + m * 40 + kq]) =
                *reinterpret_cast<const ushort4*>(A + (size_t)(bm + m) * K + kk + kq);
        }
        {
            const int n = t;
            const u16* bp = Wt + (size_t)n * K + kk;
            u16* dst = &BsB[buf * 256 * 40 + n * 40];
            #pragma unroll
            for (int j = 0; j < 4; ++j)
                *reinterpret_cast<short8*>(dst + j * 8) =
                    *reinterpret_cast<const short8*>(bp + j * 8);
        }
    };

    stage(0, 0);
    __syncthreads();
    int buf = 0;
    for (int kk = 0; kk < K; kk += 32) {
        if (kk + 32 < K) stage(buf ^ 1, kk + 32);
        short8 bf[8];
        #pragma unroll
        for (int ni = 0; ni < 8; ++ni)
            bf[ni] = *reinterpret_cast<const short8*>(
                &BsB[buf * 256 * 40 + (wc * 128 + ni * 16 + lq) * 40 + lg * 8]);
        const short8 af = *reinterpret_cast<const short8*>(
            &AsB[buf * 32 * 40 + (wr * 16 + lq) * 40 + lg * 8]);
        #pragma unroll
        for (int ni = 0; ni < 8; ++ni)
            acc[ni] = __builtin_amdgcn_mfma_f32_16x16x32_bf16(af, bf[ni], acc[ni], 0, 0, 0);
        __syncthreads();
        buf ^= 1;
    }

    #pragma unroll
    for (int ni = 0; ni < 8; ++ni) {
        const int cg = wc * 128 + ni * 16 + lq;
        const int rl0 = wr * 16 + lg * 4;
        const float bv = bias[cg];
        #pragma unroll
        for (int r = 0; r < 4; ++r)
            lnb[(rl0 + r) * 260 + cg] = acc[ni][r] + bv;
    }
    __syncthreads();

    #pragma unroll
    for (int rr = 0; rr < 8; ++rr) {
        const int rl = w * 8 + rr;
        const int row = bm + rl;
        float xv[4];
        float4 yv = *reinterpret_cast<const float4*>(&lnb[rl * 260 + l * 4]);
        float rv[4];
        load4(xb + (size_t)row * kD + l * 4, rv);
        xv[0] = yv.x + rv[0]; xv[1] = yv.y + rv[1];
        xv[2] = yv.z + rv[2]; xv[3] = yv.w + rv[3];
        float s = xv[0] + xv[1] + xv[2] + xv[3];
        float q = xv[0]*xv[0] + xv[1]*xv[1] + xv[2]*xv[2] + xv[3]*xv[3];
        #pragma unroll
        for (int off = 1; off < 64; off <<= 1) {
            s += __shfl_xor(s, off);
            q += __shfl_xor(q, off);
        }
        const float mean = s * (1.0f / kD);
        const float var = q * (1.0f / kD) - mean * mean;
        const float rs = rsqrtf(var + kEps);
        float gv[4], bv[4];
        load4(gam + l * 4, gv);
        load4(bet + l * 4, bv);
        float4 o;
        o.x = (xv[0] - mean) * rs * gv[0] + bv[0];
        o.y = (xv[1] - mean) * rs * gv[1] + bv[1];
        o.z = (xv[2] - mean) * rs * gv[2] + bv[2];
        o.w = (xv[3] - mean) * rs * gv[3] + bv[3];
        *reinterpret_cast<float4*>(out + (size_t)row * kD + l * 4) = o;
    }
}

// ---------- attention: LDS-shared K/V, T14 issue-early/write-late staging ----------
// Block = 512 thr = 8 waves x 32 q-rows; per tile one coalesced 8KB stage.
// Loads for tile t+1 issue BEFORE tile t's compute; ds_write happens AFTER
// (vmcnt wait then lands behind ~600cy of MFMA+exp instead of in front).
__global__ __launch_bounds__(512) void attn_mfma(
    const u16* __restrict__ Qb, const u16* __restrict__ Kb,
    const u16* __restrict__ VTb, const unsigned char* __restrict__ mask,
    const u32* __restrict__ Mw, float* __restrict__ O)
{
    __shared__ u16 Ks[2][64 * 40];   // K tile rows padded to 40 u16
    __shared__ u16 Vs[2][32 * 72];   // V^T tile rows padded to 72 u16
    const int t = threadIdx.x;
    const int w = t >> 6, l = t & 63;
    const int q32 = l & 31, hi = l >> 5;
    const int bid = blockIdx.x;
    const int h = bid & 7;
    const int half = (bid >> 3) & 1;
    const int b = bid >> 4;
    const int qrow = half * 256 + w * 32 + q32;

    const u16* qp = Qb + ((size_t)(b * kNL) + qrow) * kD + h * kHD;
    const short8 qf0 = *reinterpret_cast<const short8*>(qp + hi * 8);
    const short8 qf1 = *reinterpret_cast<const short8*>(qp + 16 + hi * 8);

    const u16* kbase  = Kb  + ((size_t)b * kS) * kD + h * kHD;
    const u16* vtbase = VTb + ((size_t)(b * kH + h) * kHD) * kS;
    const unsigned char* mrow = mask + ((size_t)(b * kNL) + qrow) * kS;
    const u32 mbits = Mw[b * kNL + qrow];

    f32x16 acc = fzero16();
    float l_run = 0.f;

    // per-thread staging role (fixed): t<256 -> K row r, col c; else V row r, col c
    const bool isK = (t < 256);
    const int sr = isK ? (t >> 2) : ((t - 256) >> 3);
    const int sc = isK ? (t & 3) : ((t - 256) & 7);
    const u16* sgp = isK ? (kbase + (size_t)sr * kD + sc * 8)
                         : (vtbase + (size_t)sr * kS + sc * 8);

    auto stage_load = [&](int kt) -> short8 {
        const int key0 = kt * 64;
        return isK ? *reinterpret_cast<const short8*>(sgp + (size_t)key0 * kD)
                   : *reinterpret_cast<const short8*>(sgp + key0);
    };
    auto stage_write = [&](int buf, short8 v) {
        if (isK) *reinterpret_cast<short8*>(&Ks[buf][sr * 40 + sc * 8]) = v;
        else     *reinterpret_cast<short8*>(&Vs[buf][sr * 72 + sc * 8]) = v;
    };

#define HALFG(kfA, kfB, vfA, vfB, keyh) do {                                   \
        f32x16 s = __builtin_amdgcn_mfma_f32_32x32x16_bf16(kfA, qf0, fzero16(), 0, 0, 0); \
        s = __builtin_amdgcn_mfma_f32_32x32x16_bf16(kfB, qf1, s, 0, 0, 0);     \
        float e[16];                                                           \
        _Pragma("unroll")                                                      \
        for (int n = 0; n < 16; ++n) e[n] = __builtin_amdgcn_exp2f(s[n]);      \
        if (cold) {                                                            \
            _Pragma("unroll")                                                  \
            for (int n = 0; n < 16; ++n) {                                     \
                const int key = (keyh) + (n & 3) + 8 * (n >> 2) + 4 * hi;      \
                if (mrow[key]) e[n] = 0.f;                                     \
            }                                                                  \
        }                                                                      \
        u32 pk[8];                                                             \
        _Pragma("unroll")                                                      \
        for (int qd = 0; qd < 4; ++qd) {                                       \
            l_run += (e[4*qd] + e[4*qd+1]) + (e[4*qd+2] + e[4*qd+3]);          \
            pk[2*qd]   = packbf(e[4*qd],   e[4*qd+1]);                         \
            pk[2*qd+1] = packbf(e[4*qd+2], e[4*qd+3]);                         \
        }                                                                      \
        {                                                                      \
            u32 xa = pk[0], ya = pk[2], xb_ = pk[1], yb_ = pk[3];              \
            asm("v_permlane32_swap_b32 %0, %1" : "+v"(xa), "+v"(ya));          \
            asm("v_permlane32_swap_b32 %0, %1" : "+v"(xb_), "+v"(yb_));        \
            const short8 pb = __builtin_bit_cast(short8, (u32x4){xa, xb_, ya, yb_}); \
            __builtin_amdgcn_s_setprio(1);                                     \
            acc = __builtin_amdgcn_mfma_f32_32x32x16_bf16(vfA, pb, acc, 0, 0, 0); \
            __builtin_amdgcn_s_setprio(0);                                     \
        }                                                                      \
        {                                                                      \
            u32 xa = pk[4], ya = pk[6], xb_ = pk[5], yb_ = pk[7];              \
            asm("v_permlane32_swap_b32 %0, %1" : "+v"(xa), "+v"(ya));          \
            asm("v_permlane32_swap_b32 %0, %1" : "+v"(xb_), "+v"(yb_));        \
            const short8 pb = __builtin_bit_cast(short8, (u32x4){xa, xb_, ya, yb_}); \
            __builtin_amdgcn_s_setprio(1);                                     \
            acc = __builtin_amdgcn_mfma_f32_32x32x16_bf16(vfB, pb, acc, 0, 0, 0); \
            __builtin_amdgcn_s_setprio(0);                                     \
        }                                                                      \
} while (0)

    {   // prologue: stage tile 0
        short8 s0 = stage_load(0);
        stage_write(0, s0);
    }
    __syncthreads();
    int buf = 0;
    for (int kt = 0; kt < 24; ++kt) {
        short8 nxt;
        const bool have_next = (kt + 1 < 24);
        if (have_next) nxt = stage_load(kt + 1);   // ISSUE EARLY (regs only)
        const int key0 = kt * 64;
        const bool cold = __any(((mbits >> kt) & 1u) != 0u);
        const short8 a0 = *reinterpret_cast<const short8*>(&Ks[buf][q32 * 40 + hi * 8]);
        const short8 a1 = *reinterpret_cast<const short8*>(&Ks[buf][q32 * 40 + 16 + hi * 8]);
        const short8 a2 = *reinterpret_cast<const short8*>(&Ks[buf][(32 + q32) * 40 + hi * 8]);
        const short8 a3 = *reinterpret_cast<const short8*>(&Ks[buf][(32 + q32) * 40 + 16 + hi * 8]);
        const short8 v0 = *reinterpret_cast<const short8*>(&Vs[buf][q32 * 72 + hi * 8]);
        const short8 v1 = *reinterpret_cast<const short8*>(&Vs[buf][q32 * 72 + 16 + hi * 8]);
        const short8 v2 = *reinterpret_cast<const short8*>(&Vs[buf][q32 * 72 + 32 + hi * 8]);
        const short8 v3 = *reinterpret_cast<const short8*>(&Vs[buf][q32 * 72 + 48 + hi * 8]);
        HALFG(a0, a1, v0, v1, key0);
        HALFG(a2, a3, v2, v3, key0 + 32);
        if (have_next) stage_write(buf ^ 1, nxt);  // WRITE LATE (vmcnt hidden)
        __syncthreads();
        buf ^= 1;
    }
#undef HALFG

    l_run += __shfl_xor(l_run, 32);
    const float inv = (l_run > 0.f) ? 1.f / l_run : 0.f;
    float* orow = O + ((size_t)(b * kNL) + qrow) * kD + h * kHD;
    #pragma unroll
    for (int qd = 0; qd < 4; ++qd) {
        float4 o = {acc[4*qd+0] * inv, acc[4*qd+1] * inv,
                    acc[4*qd+2] * inv, acc[4*qd+3] * inv};
        *reinterpret_cast<float4*>(orow + qd * 8 + 4 * hi) = o;
    }
}

// out = LayerNorm(a + r) * gamma + beta, dual f32 + bf16 outputs.
__global__ __launch_bounds__(256) void ln_k(
    const float* __restrict__ a_, const float* __restrict__ r,
    const float* __restrict__ gam, const float* __restrict__ bet,
    float* __restrict__ out_, u16* __restrict__ outh)
{
    const int row = blockIdx.x * 4 + (threadIdx.x >> 6);
    const int lane = threadIdx.x & 63;
    const size_t base = (size_t)row * kD + lane * 4;
    float xv[4];
    load4(a_ + base, xv);
    float rv[4];
    load4(r + base, rv);
    #pragma unroll
    for (int t = 0; t < 4; ++t) xv[t] += rv[t];
    float s = xv[0] + xv[1] + xv[2] + xv[3];
    float q = xv[0]*xv[0] + xv[1]*xv[1] + xv[2]*xv[2] + xv[3]*xv[3];
    #pragma unroll
    for (int off = 1; off < 64; off <<= 1) {
        s += __shfl_xor(s, off);
        q += __shfl_xor(q, off);
    }
    const float mean = s * (1.0f / kD);
    const float var = q * (1.0f / kD) - mean * mean;
    const float rs = rsqrtf(var + kEps);
    float gv[4], bv[4];
    load4(gam + lane * 4, gv);
    load4(bet + lane * 4, bv);
    float y[4];
    #pragma unroll
    for (int t = 0; t < 4; ++t) y[t] = (xv[t] - mean) * rs * gv[t] + bv[t];
    float4 o = {y[0], y[1], y[2], y[3]};
    *reinterpret_cast<float4*>(out_ + base) = o;
    ushort4 ob = {f2bh(y[0]), f2bh(y[1]), f2bh(y[2]), f2bh(y[3])};
    *reinterpret_cast<ushort4*>(outh + base) = ob;
}

extern "C" void kernel_launch(void* const* d_in, const int* in_sizes, int n_in,
                              void* d_out, int out_size, void* d_ws, size_t ws_size,
                              hipStream_t stream)
{
    const float* node_x = (const float*)d_in[0];
    const float* edge_x = (const float*)d_in[1];
    const unsigned char* mask = (const unsigned char*)d_in[2];
    const float* W1  = (const float*)d_in[3];
    const float* b1  = (const float*)d_in[4];
    const float* W2  = (const float*)d_in[5];
    const float* b2  = (const float*)d_in[6];
    const float* l1w = (const float*)d_in[7];
    const float* l1b = (const float*)d_in[8];
    const float* l2w = (const float*)d_in[9];
    const float* l2b = (const float*)d_in[10];
    const float* g1  = (const float*)d_in[11];
    const float* be1 = (const float*)d_in[12];
    const float* g2  = (const float*)d_in[13];
    const float* be2 = (const float*)d_in[14];

    char* w = (char*)d_ws;
    u16*   qb  = (u16*)(w);                      // q bf16 4 MB   [0,4); later fh bf16
    u16*   wt1 = (u16*)(w + (4u<<20));           // 768x256 bf16
    u16*   wt2 = (u16*)(w + (4u<<20) + 393216);
    u16*   wt3 = (u16*)(w + (4u<<20) + 655360);
    u16*   wt4 = (u16*)(w + (4u<<20) + 786432);
    u32*   mw  = (u32*)(w + (4u<<20) + 917504);  // mask bitmap 32 KB
    u16*   nxb = (u16*)(w + (5u<<20));           // node bf16 4 MB  [5,9)
    u16*   exb = (u16*)(w + (9u<<20));           // edge bf16 8 MB  [9,17); later xbh
    u16*   kb  = (u16*)(w + (17u<<20));          // K bf16 12 MB    [17,30)
    u16*   vt  = (u16*)(w + (30u<<20));          // V^T bf16 12 MB  [30,43)
    float* cx  = (float*)(w + (43u<<20));        // ctx f32 8 MB    [43,52)
    float* xb  = (float*)(w + (52u<<20));        // x after LN1 f32 [52,61)
    u16*   xbh = exb;                            // LN1 bf16 out (edge_bf dead)
    u16*   fh  = qb;                             // ffn hidden bf16 (qb dead)

    prep_k<<<8640, 256, 0, stream>>>(
        W1, W2, l1w, l2w, node_x, edge_x, (const u32*)mask,
        wt1, wt2, wt3, wt4, nxb, exb, mw);
    qkv_both<<<896, 256, 0, stream>>>(nxb, exb, wt1, wt2, b1, b2, qb, kb, vt);
    attn_mfma<<<kB * 2 * 8, 512, 0, stream>>>(qb, kb, vt, mask, mw, cx);
    ln_k<<<kM1 / 4, 256, 0, stream>>>(node_x, cx, g1, be1, xb, xbh);
    ffn1_k<<<dim3(kM1 / 64, 2), 256, 0, stream>>>(xbh, wt3, l1b, fh);
    ffn2_ln2_k<<<kM1 / 32, 256, 0, stream>>>(fh, wt4, l2b, xb, g2, be2, (float*)d_out);
}